// Round 18
// baseline (320.318 us; speedup 1.0000x reference)
//
#include <hip/hip_runtime.h>
#include <hip/hip_bf16.h>

#define BN_EPS 1e-5f
#define CCHUNK 4096    // edges per partition block

__device__ __forceinline__ ushort f2bf(float f) {
    unsigned int u = __float_as_uint(f);
    u += 0x7FFFu + ((u >> 16) & 1u);
    return (ushort)(u >> 16);
}

// ---------------- bucket histogram (buckets of 128 dst nodes) + graph bounds ----------------
__global__ void k_bhist(const int* __restrict__ dst, int E, int nb, int* __restrict__ bktcnt,
                        const int* __restrict__ batch, int n, int G, int* __restrict__ gs) {
    int gid = blockIdx.x * blockDim.x + threadIdx.x;
    if (gid <= G) {
        int lo = 0, hi = n;
        while (lo < hi) { int mid = (lo + hi) >> 1; if (batch[mid] < gid) lo = mid + 1; else hi = mid; }
        gs[gid] = lo;
    }
    __shared__ int lh[1024];
    for (int j = threadIdx.x; j < nb; j += 256) lh[j] = 0;
    __syncthreads();
    for (int i = blockIdx.x * blockDim.x + threadIdx.x; i < E; i += gridDim.x * blockDim.x)
        atomicAdd(&lh[dst[i] >> 7], 1);
    __syncthreads();
    for (int j = threadIdx.x; j < nb; j += 256) {
        int c = lh[j];
        if (c) atomicAdd(&bktcnt[j], c);
    }
}

// ---------------- single-block exclusive scan of bucket counts ----------------
__global__ void k_bscan(const int* __restrict__ bktcnt, int nb, int N,
                        int* __restrict__ bktoff, int* __restrict__ gpos,
                        int* __restrict__ rowptr) {
    __shared__ int sh[256];
    int tid = threadIdx.x;
    int base = tid * 4;
    int v[4]; int tsum = 0;
    #pragma unroll
    for (int k = 0; k < 4; ++k) {
        int i = base + k;
        v[k] = (i < nb) ? bktcnt[i] : 0;
        tsum += v[k];
    }
    sh[tid] = tsum;
    __syncthreads();
    for (int off = 1; off < 256; off <<= 1) {
        int add = (tid >= off) ? sh[tid - off] : 0;
        __syncthreads();
        sh[tid] += add;
        __syncthreads();
    }
    int excl = sh[tid] - tsum;
    #pragma unroll
    for (int k = 0; k < 4; ++k) {
        int i = base + k;
        if (i <= nb) {
            bktoff[i] = excl;
            if (i < nb) gpos[i] = excl;
        }
        excl += v[k];
    }
    if (tid == 255) rowptr[N] = sh[255];   // total = E
}

// ---------------- partition edges into bucket-contiguous order ----------------
// per-wave sub-histograms + per-wave cursor sub-ranges: LDS atomics only collide within a wave
__global__ void k_partition(const int* __restrict__ src, const int* __restrict__ dst,
                            int E, int nb, int sb,
                            int* __restrict__ gpos, unsigned int* __restrict__ eb) {
    __shared__ int lh[4][1024];
    int tid = threadIdx.x;
    int wv = tid >> 6;
    int e0 = blockIdx.x * CCHUNK;
    int cnt = min(CCHUNK, E - e0);
    for (int j = tid; j < nb; j += 256) {
        lh[0][j] = 0; lh[1][j] = 0; lh[2][j] = 0; lh[3][j] = 0;
    }
    __syncthreads();
    for (int k = tid; k < cnt; k += 256)
        atomicAdd(&lh[wv][dst[e0 + k] >> 7], 1);
    __syncthreads();
    for (int j = tid; j < nb; j += 256) {
        int c0 = lh[0][j], c1 = lh[1][j], c2 = lh[2][j], c3 = lh[3][j];
        int c = c0 + c1 + c2 + c3;
        int base = c ? atomicAdd(&gpos[j], c) : 0;   // reserve contiguous run for this block
        lh[0][j] = base;                              // per-wave cursor bases
        lh[1][j] = base + c0;
        lh[2][j] = base + c0 + c1;
        lh[3][j] = base + c0 + c1 + c2;
    }
    __syncthreads();
    for (int k = tid; k < cnt; k += 256) {
        int d = dst[e0 + k];
        unsigned int s = (unsigned int)src[e0 + k];
        int pos = atomicAdd(&lh[wv][d >> 7], 1);      // same wave counted these edges in phase 1
        eb[pos] = (((unsigned int)(d & 127)) << sb) | s;
    }
}

// ---------------- per-bucket: deg -> rowptr + dis (LDS hist + scan) ----------------
__global__ void k_row(const unsigned int* __restrict__ eb, const int* __restrict__ bktoff,
                      int sb, int N, float* __restrict__ dis, int* __restrict__ rowptr) {
    __shared__ int h[128];
    __shared__ int p[128];
    int tid = threadIdx.x;
    int b = blockIdx.x;
    if (tid < 128) h[tid] = 0;
    __syncthreads();
    int e0 = bktoff[b], e1 = bktoff[b + 1];
    for (int e = e0 + tid; e < e1; e += 256)
        atomicAdd(&h[(eb[e] >> sb) & 127], 1);
    __syncthreads();
    if (tid < 128) p[tid] = h[tid];
    __syncthreads();
    for (int off = 1; off < 128; off <<= 1) {
        int add = (tid < 128 && tid >= off) ? p[tid - off] : 0;
        __syncthreads();
        if (tid < 128) p[tid] += add;
        __syncthreads();
    }
    if (tid < 128) {
        int d = b * 128 + tid;
        if (d < N) {
            rowptr[d] = e0 + p[tid] - h[tid];
            dis[d] = rsqrtf((float)(h[tid] + 1));   // +1 self-loop
        }
    }
}

// ---------------- per-bucket CSR fill: cw[slot] = {src, f32 weight} ----------------
__global__ void k_csrfill(const unsigned int* __restrict__ eb, const int* __restrict__ bktoff,
                          const int* __restrict__ rowptr, const float* __restrict__ dis,
                          int sb, unsigned int smask, int N, int2* __restrict__ cw) {
    __shared__ int nc[128];
    __shared__ float dl[128];
    int tid = threadIdx.x;
    int b = blockIdx.x;
    if (tid < 128) {
        int d = b * 128 + tid;
        nc[tid] = (d < N) ? rowptr[d] : 0;
        dl[tid] = (d < N) ? dis[d] : 1.f;
    }
    __syncthreads();
    int e0 = bktoff[b], e1 = bktoff[b + 1];
    for (int e = e0 + tid; e < e1; e += 256) {
        unsigned int v = eb[e];
        int dloc = (v >> sb) & 127;
        int s = (int)(v & smask);
        int slot = atomicAdd(&nc[dloc], 1);
        cw[slot] = make_int2(s, __float_as_int(dis[s] * dl[dloc]));
    }
}

// ---------------- tiled dense transform: tb = f(X) @ W (bf16 out) ----------------
// stats != nullptr: compute BN params per block from raw stats and apply BN+ReLU to input.
__global__ void k_matmul64t(const float* __restrict__ X, const float* __restrict__ W,
                            const float* __restrict__ stats, const float* __restrict__ gamma,
                            const float* __restrict__ beta, int n, ushort* __restrict__ tb) {
    __shared__ float Xs[64][68];
    __shared__ float Ws[64][64];
    __shared__ float bnpL[128];
    const int tid = threadIdx.x;
    const int rowbase = blockIdx.x * 64;
    const bool hasbn = (stats != nullptr);

    {
        const float4* W4 = (const float4*)W;
        float4* Ws4 = (float4*)&Ws[0][0];
        #pragma unroll
        for (int k = 0; k < 4; ++k) Ws4[tid + 256 * k] = W4[tid + 256 * k];
    }
    if (hasbn) {
        if (tid < 64) {
            float inv_n = 1.f / (float)n;
            float mean = stats[tid] * inv_n;
            float var = stats[64 + tid] * inv_n - mean * mean;
            float s = gamma[tid] * rsqrtf(var + BN_EPS);
            bnpL[tid] = s;
            bnpL[64 + tid] = beta[tid] - mean * s;
        }
        __syncthreads();
    }
    {
        const int r  = tid >> 2;
        const int c0 = (tid & 3) * 16;
        const int row = rowbase + r;
        #pragma unroll
        for (int j = 0; j < 4; ++j) {
            float4 v;
            if (row < n) v = *(const float4*)&X[(size_t)row * 64 + c0 + 4 * j];
            else v = make_float4(0.f, 0.f, 0.f, 0.f);
            float vv[4] = {v.x, v.y, v.z, v.w};
            #pragma unroll
            for (int i = 0; i < 4; ++i) {
                int c = c0 + 4 * j + i;
                float f = vv[i];
                if (hasbn) f = fmaxf(0.f, fmaf(f, bnpL[c], bnpL[64 + c]));
                Xs[c][r] = f;
            }
        }
    }
    __syncthreads();

    const int r0 = (tid & 15) * 4;
    const int c0 = (tid >> 4) * 4;
    float acc[4][4];
    #pragma unroll
    for (int i = 0; i < 4; ++i)
        #pragma unroll
        for (int j = 0; j < 4; ++j) acc[i][j] = 0.f;

    #pragma unroll 4
    for (int k = 0; k < 64; ++k) {
        float4 xv = *(const float4*)&Xs[k][r0];
        float4 wv = *(const float4*)&Ws[k][c0];
        float xa[4] = {xv.x, xv.y, xv.z, xv.w};
        float wa[4] = {wv.x, wv.y, wv.z, wv.w};
        #pragma unroll
        for (int i = 0; i < 4; ++i)
            #pragma unroll
            for (int j = 0; j < 4; ++j)
                acc[i][j] = fmaf(xa[i], wa[j], acc[i][j]);
    }

    #pragma unroll
    for (int i = 0; i < 4; ++i) {
        int row = rowbase + r0 + i;
        if (row < n) {
            ushort4 o;
            o.x = f2bf(acc[i][0]); o.y = f2bf(acc[i][1]);
            o.z = f2bf(acc[i][2]); o.w = f2bf(acc[i][3]);
            *(ushort4*)&tb[(size_t)row * 64 + c0] = o;
        }
    }
}

// ---------------- aggregation: one wave per dst node, 8 edges/iter via 8-lane groups -------
__global__ void k_gather(const int2* __restrict__ cw, const int* __restrict__ rowptr,
                         const float* __restrict__ dis, const ushort* __restrict__ tb,
                         int n, float* __restrict__ a) {
    int lane = threadIdx.x & 63;
    int wave = threadIdx.x >> 6;
    int row = blockIdx.x * 4 + wave;
    if (row >= n) return;
    const int fl = lane & 7;    // feature block: features 8fl..8fl+7
    const int o  = lane >> 3;   // group: edge index j*8+o
    int e0 = rowptr[row], e1 = rowptr[row + 1];
    float acc[8];
    #pragma unroll
    for (int i = 0; i < 8; ++i) acc[i] = 0.f;
    for (int base = e0; base < e1; base += 64) {
        int cnt = min(64, e1 - base);
        int2 pw = (lane < cnt) ? cw[base + lane] : make_int2(0, 0);
        int nq = (cnt + 7) >> 3;
        for (int j = 0; j < nq; ++j) {
            int idx = 8 * j + o;
            int s = __shfl(pw.x, idx);
            float w = __uint_as_float((unsigned int)__shfl(pw.y, idx)); // 0 beyond cnt
            uint4 tv = *(const uint4*)&tb[(size_t)s * 64 + 8 * fl];
            acc[0] = fmaf(__uint_as_float(tv.x << 16),         w, acc[0]);
            acc[1] = fmaf(__uint_as_float(tv.x & 0xffff0000u), w, acc[1]);
            acc[2] = fmaf(__uint_as_float(tv.y << 16),         w, acc[2]);
            acc[3] = fmaf(__uint_as_float(tv.y & 0xffff0000u), w, acc[3]);
            acc[4] = fmaf(__uint_as_float(tv.z << 16),         w, acc[4]);
            acc[5] = fmaf(__uint_as_float(tv.z & 0xffff0000u), w, acc[5]);
            acc[6] = fmaf(__uint_as_float(tv.w << 16),         w, acc[6]);
            acc[7] = fmaf(__uint_as_float(tv.w & 0xffff0000u), w, acc[7]);
        }
    }
    #pragma unroll
    for (int i = 0; i < 8; ++i) {
        acc[i] += __shfl_xor(acc[i], 8);
        acc[i] += __shfl_xor(acc[i], 16);
        acc[i] += __shfl_xor(acc[i], 32);
    }
    if (o == 0) {
        float dr = dis[row];
        float d2 = dr * dr;
        uint4 ts = *(const uint4*)&tb[(size_t)row * 64 + 8 * fl];
        acc[0] = fmaf(__uint_as_float(ts.x << 16),         d2, acc[0]);
        acc[1] = fmaf(__uint_as_float(ts.x & 0xffff0000u), d2, acc[1]);
        acc[2] = fmaf(__uint_as_float(ts.y << 16),         d2, acc[2]);
        acc[3] = fmaf(__uint_as_float(ts.y & 0xffff0000u), d2, acc[3]);
        acc[4] = fmaf(__uint_as_float(ts.z << 16),         d2, acc[4]);
        acc[5] = fmaf(__uint_as_float(ts.z & 0xffff0000u), d2, acc[5]);
        acc[6] = fmaf(__uint_as_float(ts.w << 16),         d2, acc[6]);
        acc[7] = fmaf(__uint_as_float(ts.w & 0xffff0000u), d2, acc[7]);
        *(float4*)&a[(size_t)row * 64 + 8 * fl]     = make_float4(acc[0], acc[1], acc[2], acc[3]);
        *(float4*)&a[(size_t)row * 64 + 8 * fl + 4] = make_float4(acc[4], acc[5], acc[6], acc[7]);
    }
}

// ---------------- BatchNorm stats (vectorized float4) ----------------
__global__ void k_stats(const float* __restrict__ a, int n, float* __restrict__ stats) {
    __shared__ float ls[128];
    int tid = threadIdx.x;
    if (tid < 128) ls[tid] = 0.f;
    __syncthreads();
    int c0 = (tid & 15) * 4;      // column group of 4
    int rg = tid >> 4;            // 16 rows per block-iter
    float s[4] = {0.f, 0.f, 0.f, 0.f};
    float q[4] = {0.f, 0.f, 0.f, 0.f};
    for (int r = blockIdx.x * 16 + rg; r < n; r += gridDim.x * 16) {
        float4 v = *(const float4*)&a[(size_t)r * 64 + c0];
        s[0] += v.x; q[0] = fmaf(v.x, v.x, q[0]);
        s[1] += v.y; q[1] = fmaf(v.y, v.y, q[1]);
        s[2] += v.z; q[2] = fmaf(v.z, v.z, q[2]);
        s[3] += v.w; q[3] = fmaf(v.w, v.w, q[3]);
    }
    #pragma unroll
    for (int i = 0; i < 4; ++i) {
        atomicAdd(&ls[c0 + i], s[i]);
        atomicAdd(&ls[64 + c0 + i], q[i]);
    }
    __syncthreads();
    if (tid < 128) atomicAdd(&stats[tid], ls[tid]);
}

// ---------------- global mean pool (computes BN params per block, fused BN+ReLU) ----------
__global__ void k_pool2(const float* __restrict__ a, const float* __restrict__ stats,
                        const float* __restrict__ gamma, const float* __restrict__ beta,
                        const int* __restrict__ gs, int n, int G, float* __restrict__ out) {
    __shared__ float bnpL[128];
    int tid = threadIdx.x;
    if (tid < 64) {
        float inv_n = 1.f / (float)n;
        float mean = stats[tid] * inv_n;
        float var = stats[64 + tid] * inv_n - mean * mean;
        float s = gamma[tid] * rsqrtf(var + BN_EPS);
        bnpL[tid] = s;
        bnpL[64 + tid] = beta[tid] - mean * s;
    }
    __syncthreads();
    int lane = tid & 63;
    int wave = tid >> 6;
    int g = blockIdx.x * 4 + wave;
    if (g >= G) return;
    int s = gs[g], e = gs[g + 1];
    float sc = bnpL[lane], of = bnpL[64 + lane];
    float acc = 0.f;
    for (int r = s; r < e; ++r)
        acc += fmaxf(0.f, fmaf(a[(size_t)r * 64 + lane], sc, of));
    out[(size_t)g * 64 + lane] = acc / (float)max(e - s, 1);
}

// ---------------- launch ----------------
extern "C" void kernel_launch(void* const* d_in, const int* in_sizes, int n_in,
                              void* d_out, int out_size, void* d_ws, size_t ws_size,
                              hipStream_t stream) {
    const float* x     = (const float*)d_in[0];
    const int*   ei    = (const int*)d_in[1];
    const int*   batch = (const int*)d_in[2];
    const float* W1    = (const float*)d_in[3];
    const float* g1    = (const float*)d_in[5];
    const float* bt1   = (const float*)d_in[6];
    const float* W2    = (const float*)d_in[7];
    const float* g2    = (const float*)d_in[9];
    const float* bt2   = (const float*)d_in[10];

    const int N = in_sizes[0] / 64;
    const int E = in_sizes[1] / 2;
    const int G = out_size / 64;

    const int* src = ei;
    const int* dst = ei + E;

    const int nb = (N + 127) >> 7;           // buckets of 128 dst nodes (nb <= 1024)
    int sb = 0; while ((1 << sb) < N) ++sb;  // bits to hold src id
    const unsigned int smask = (1u << sb) - 1u;

    ushort* tb        = (ushort*)d_ws;                       // N*64 bf16
    float* a          = (float*)(tb + (size_t)N * 64);       // N*64 f32
    int2*  cw         = (int2*)(a + (size_t)N * 64);         // E {src, w}
    unsigned int* eb  = (unsigned int*)(cw + E);             // E (bucketed packed edges)
    float* dis        = (float*)(eb + E);                    // N
    int*   rowptr     = (int*)(dis + N);                     // N+1
    // zeroed region (one memset): bktcnt | stats(256)
    int*   bktcnt     = rowptr + N + 1;                      // nb
    float* stats      = (float*)(bktcnt + nb);               // 256 (two sets of 128)
    int*   bktoff     = (int*)(stats + 256);                 // nb+1
    int*   gpos       = bktoff + nb + 1;                     // nb
    int*   gs         = gpos + nb;                           // G+1

    float* out = (float*)d_out;

    const int mmBlocks = (N + 63) / 64;
    const int gaBlocks = (N + 3) / 4;
    const int nchunks  = (E + CCHUNK - 1) / CCHUNK;

    // ---- CSR build (bucketed, write-local) ----
    hipMemsetAsync(bktcnt, 0, (size_t)(nb + 256) * sizeof(int), stream);
    k_bhist<<<512, 256, 0, stream>>>(dst, E, nb, bktcnt, batch, N, G, gs);
    k_bscan<<<1, 256, 0, stream>>>(bktcnt, nb, N, bktoff, gpos, rowptr);
    k_partition<<<nchunks, 256, 0, stream>>>(src, dst, E, nb, sb, gpos, eb);
    k_row<<<nb, 256, 0, stream>>>(eb, bktoff, sb, N, dis, rowptr);
    k_csrfill<<<nb, 256, 0, stream>>>(eb, bktoff, rowptr, dis, sb, smask, N, cw);

    // ---- layer 1 ----
    k_matmul64t<<<mmBlocks, 256, 0, stream>>>(x, W1, nullptr, nullptr, nullptr, N, tb);
    k_gather<<<gaBlocks, 256, 0, stream>>>(cw, rowptr, dis, tb, N, a);
    k_stats<<<1024, 256, 0, stream>>>(a, N, stats);

    // ---- layer 2 (BN1+ReLU fused into matmul input; BN params from raw stats) ----
    k_matmul64t<<<mmBlocks, 256, 0, stream>>>(a, W2, stats, g1, bt1, N, tb);
    k_gather<<<gaBlocks, 256, 0, stream>>>(cw, rowptr, dis, tb, N, a);
    k_stats<<<1024, 256, 0, stream>>>(a, N, stats + 128);

    // ---- pool (BN2+ReLU fused; BN params from raw stats) ----
    k_pool2<<<(G + 3) / 4, 256, 0, stream>>>(a, stats + 128, g2, bt2, gs, N, G, out);
}

// Round 19
// 283.740 us; speedup vs baseline: 1.1289x; 1.1289x over previous
//
#include <hip/hip_runtime.h>
#include <hip/hip_bf16.h>

#define BN_EPS 1e-5f
#define CCHUNK 4096    // edges per partition block

__device__ __forceinline__ ushort f2bf(float f) {
    unsigned int u = __float_as_uint(f);
    u += 0x7FFFu + ((u >> 16) & 1u);
    return (ushort)(u >> 16);
}

// ---------------- bucket histogram (buckets of 128 dst nodes) + graph bounds ----------------
__global__ void k_bhist(const int* __restrict__ dst, int E, int nb, int* __restrict__ bktcnt,
                        const int* __restrict__ batch, int n, int G, int* __restrict__ gs) {
    int gid = blockIdx.x * blockDim.x + threadIdx.x;
    if (gid <= G) {
        int lo = 0, hi = n;
        while (lo < hi) { int mid = (lo + hi) >> 1; if (batch[mid] < gid) lo = mid + 1; else hi = mid; }
        gs[gid] = lo;
    }
    __shared__ int lh[1024];
    for (int j = threadIdx.x; j < nb; j += 256) lh[j] = 0;
    __syncthreads();
    for (int i = blockIdx.x * blockDim.x + threadIdx.x; i < E; i += gridDim.x * blockDim.x)
        atomicAdd(&lh[dst[i] >> 7], 1);
    __syncthreads();
    for (int j = threadIdx.x; j < nb; j += 256) {
        int c = lh[j];
        if (c) atomicAdd(&bktcnt[j], c);
    }
}

// ---------------- single-block exclusive scan of bucket counts ----------------
__global__ void k_bscan(const int* __restrict__ bktcnt, int nb, int N,
                        int* __restrict__ bktoff, int* __restrict__ gpos,
                        int* __restrict__ rowptr) {
    __shared__ int sh[256];
    int tid = threadIdx.x;
    int base = tid * 4;
    int v[4]; int tsum = 0;
    #pragma unroll
    for (int k = 0; k < 4; ++k) {
        int i = base + k;
        v[k] = (i < nb) ? bktcnt[i] : 0;
        tsum += v[k];
    }
    sh[tid] = tsum;
    __syncthreads();
    for (int off = 1; off < 256; off <<= 1) {
        int add = (tid >= off) ? sh[tid - off] : 0;
        __syncthreads();
        sh[tid] += add;
        __syncthreads();
    }
    int excl = sh[tid] - tsum;
    #pragma unroll
    for (int k = 0; k < 4; ++k) {
        int i = base + k;
        if (i <= nb) {
            bktoff[i] = excl;
            if (i < nb) gpos[i] = excl;
        }
        excl += v[k];
    }
    if (tid == 255) rowptr[N] = sh[255];   // total = E
}

// ---------------- partition edges into bucket-contiguous order ----------------
// per-wave sub-histograms + per-wave cursor sub-ranges: LDS atomics only collide within a wave
__global__ void k_partition(const int* __restrict__ src, const int* __restrict__ dst,
                            int E, int nb, int sb,
                            int* __restrict__ gpos, unsigned int* __restrict__ eb) {
    __shared__ int lh[4][1024];
    int tid = threadIdx.x;
    int wv = tid >> 6;
    int e0 = blockIdx.x * CCHUNK;
    int cnt = min(CCHUNK, E - e0);
    for (int j = tid; j < nb; j += 256) {
        lh[0][j] = 0; lh[1][j] = 0; lh[2][j] = 0; lh[3][j] = 0;
    }
    __syncthreads();
    for (int k = tid; k < cnt; k += 256)
        atomicAdd(&lh[wv][dst[e0 + k] >> 7], 1);
    __syncthreads();
    for (int j = tid; j < nb; j += 256) {
        int c0 = lh[0][j], c1 = lh[1][j], c2 = lh[2][j], c3 = lh[3][j];
        int c = c0 + c1 + c2 + c3;
        int base = c ? atomicAdd(&gpos[j], c) : 0;   // reserve contiguous run for this block
        lh[0][j] = base;                              // per-wave cursor bases
        lh[1][j] = base + c0;
        lh[2][j] = base + c0 + c1;
        lh[3][j] = base + c0 + c1 + c2;
    }
    __syncthreads();
    for (int k = tid; k < cnt; k += 256) {
        int d = dst[e0 + k];
        unsigned int s = (unsigned int)src[e0 + k];
        int pos = atomicAdd(&lh[wv][d >> 7], 1);      // same wave counted these edges in phase 1
        eb[pos] = (((unsigned int)(d & 127)) << sb) | s;
    }
}

// ---------------- per-bucket: deg -> rowptr + dis (LDS hist + scan) ----------------
__global__ void k_row(const unsigned int* __restrict__ eb, const int* __restrict__ bktoff,
                      int sb, int N, float* __restrict__ dis, int* __restrict__ rowptr) {
    __shared__ int h[128];
    __shared__ int p[128];
    int tid = threadIdx.x;
    int b = blockIdx.x;
    if (tid < 128) h[tid] = 0;
    __syncthreads();
    int e0 = bktoff[b], e1 = bktoff[b + 1];
    for (int e = e0 + tid; e < e1; e += 256)
        atomicAdd(&h[(eb[e] >> sb) & 127], 1);
    __syncthreads();
    if (tid < 128) p[tid] = h[tid];
    __syncthreads();
    for (int off = 1; off < 128; off <<= 1) {
        int add = (tid < 128 && tid >= off) ? p[tid - off] : 0;
        __syncthreads();
        if (tid < 128) p[tid] += add;
        __syncthreads();
    }
    if (tid < 128) {
        int d = b * 128 + tid;
        if (d < N) {
            rowptr[d] = e0 + p[tid] - h[tid];
            dis[d] = rsqrtf((float)(h[tid] + 1));   // +1 self-loop
        }
    }
}

// ---------------- per-bucket CSR fill: cw[slot] = {src, f32 weight} ----------------
__global__ void k_csrfill(const unsigned int* __restrict__ eb, const int* __restrict__ bktoff,
                          const int* __restrict__ rowptr, const float* __restrict__ dis,
                          int sb, unsigned int smask, int N, int2* __restrict__ cw) {
    __shared__ int nc[128];
    __shared__ float dl[128];
    int tid = threadIdx.x;
    int b = blockIdx.x;
    if (tid < 128) {
        int d = b * 128 + tid;
        nc[tid] = (d < N) ? rowptr[d] : 0;
        dl[tid] = (d < N) ? dis[d] : 1.f;
    }
    __syncthreads();
    int e0 = bktoff[b], e1 = bktoff[b + 1];
    for (int e = e0 + tid; e < e1; e += 256) {
        unsigned int v = eb[e];
        int dloc = (v >> sb) & 127;
        int s = (int)(v & smask);
        int slot = atomicAdd(&nc[dloc], 1);
        cw[slot] = make_int2(s, __float_as_int(dis[s] * dl[dloc]));
    }
}

// ---------------- tiled dense transform: tb = f(X) @ W (bf16 out) ----------------
// stats != nullptr: compute BN params per block from raw stats and apply BN+ReLU to input.
__global__ void k_matmul64t(const float* __restrict__ X, const float* __restrict__ W,
                            const float* __restrict__ stats, const float* __restrict__ gamma,
                            const float* __restrict__ beta, int n, ushort* __restrict__ tb) {
    __shared__ float Xs[64][68];
    __shared__ float Ws[64][64];
    __shared__ float bnpL[128];
    const int tid = threadIdx.x;
    const int rowbase = blockIdx.x * 64;
    const bool hasbn = (stats != nullptr);

    {
        const float4* W4 = (const float4*)W;
        float4* Ws4 = (float4*)&Ws[0][0];
        #pragma unroll
        for (int k = 0; k < 4; ++k) Ws4[tid + 256 * k] = W4[tid + 256 * k];
    }
    if (hasbn) {
        if (tid < 64) {
            float inv_n = 1.f / (float)n;
            float mean = stats[tid] * inv_n;
            float var = stats[64 + tid] * inv_n - mean * mean;
            float s = gamma[tid] * rsqrtf(var + BN_EPS);
            bnpL[tid] = s;
            bnpL[64 + tid] = beta[tid] - mean * s;
        }
        __syncthreads();
    }
    {
        const int r  = tid >> 2;
        const int c0 = (tid & 3) * 16;
        const int row = rowbase + r;
        #pragma unroll
        for (int j = 0; j < 4; ++j) {
            float4 v;
            if (row < n) v = *(const float4*)&X[(size_t)row * 64 + c0 + 4 * j];
            else v = make_float4(0.f, 0.f, 0.f, 0.f);
            float vv[4] = {v.x, v.y, v.z, v.w};
            #pragma unroll
            for (int i = 0; i < 4; ++i) {
                int c = c0 + 4 * j + i;
                float f = vv[i];
                if (hasbn) f = fmaxf(0.f, fmaf(f, bnpL[c], bnpL[64 + c]));
                Xs[c][r] = f;
            }
        }
    }
    __syncthreads();

    const int r0 = (tid & 15) * 4;
    const int c0 = (tid >> 4) * 4;
    float acc[4][4];
    #pragma unroll
    for (int i = 0; i < 4; ++i)
        #pragma unroll
        for (int j = 0; j < 4; ++j) acc[i][j] = 0.f;

    #pragma unroll 4
    for (int k = 0; k < 64; ++k) {
        float4 xv = *(const float4*)&Xs[k][r0];
        float4 wv = *(const float4*)&Ws[k][c0];
        float xa[4] = {xv.x, xv.y, xv.z, xv.w};
        float wa[4] = {wv.x, wv.y, wv.z, wv.w};
        #pragma unroll
        for (int i = 0; i < 4; ++i)
            #pragma unroll
            for (int j = 0; j < 4; ++j)
                acc[i][j] = fmaf(xa[i], wa[j], acc[i][j]);
    }

    #pragma unroll
    for (int i = 0; i < 4; ++i) {
        int row = rowbase + r0 + i;
        if (row < n) {
            ushort4 o;
            o.x = f2bf(acc[i][0]); o.y = f2bf(acc[i][1]);
            o.z = f2bf(acc[i][2]); o.w = f2bf(acc[i][3]);
            *(ushort4*)&tb[(size_t)row * 64 + c0] = o;
        }
    }
}

// ---------------- aggregation: one wave per dst node, 8 edges/iter via 8-lane groups -------
__global__ void k_gather(const int2* __restrict__ cw, const int* __restrict__ rowptr,
                         const float* __restrict__ dis, const ushort* __restrict__ tb,
                         int n, float* __restrict__ a) {
    int lane = threadIdx.x & 63;
    int wave = threadIdx.x >> 6;
    int row = blockIdx.x * 4 + wave;
    if (row >= n) return;
    const int fl = lane & 7;    // feature block: features 8fl..8fl+7
    const int o  = lane >> 3;   // group: edge index j*8+o
    int e0 = rowptr[row], e1 = rowptr[row + 1];
    float acc[8];
    #pragma unroll
    for (int i = 0; i < 8; ++i) acc[i] = 0.f;
    for (int base = e0; base < e1; base += 64) {
        int cnt = min(64, e1 - base);
        int2 pw = (lane < cnt) ? cw[base + lane] : make_int2(0, 0);
        int nq = (cnt + 7) >> 3;
        for (int j = 0; j < nq; ++j) {
            int idx = 8 * j + o;
            int s = __shfl(pw.x, idx);
            float w = __uint_as_float((unsigned int)__shfl(pw.y, idx)); // 0 beyond cnt
            uint4 tv = *(const uint4*)&tb[(size_t)s * 64 + 8 * fl];
            acc[0] = fmaf(__uint_as_float(tv.x << 16),         w, acc[0]);
            acc[1] = fmaf(__uint_as_float(tv.x & 0xffff0000u), w, acc[1]);
            acc[2] = fmaf(__uint_as_float(tv.y << 16),         w, acc[2]);
            acc[3] = fmaf(__uint_as_float(tv.y & 0xffff0000u), w, acc[3]);
            acc[4] = fmaf(__uint_as_float(tv.z << 16),         w, acc[4]);
            acc[5] = fmaf(__uint_as_float(tv.z & 0xffff0000u), w, acc[5]);
            acc[6] = fmaf(__uint_as_float(tv.w << 16),         w, acc[6]);
            acc[7] = fmaf(__uint_as_float(tv.w & 0xffff0000u), w, acc[7]);
        }
    }
    #pragma unroll
    for (int i = 0; i < 8; ++i) {
        acc[i] += __shfl_xor(acc[i], 8);
        acc[i] += __shfl_xor(acc[i], 16);
        acc[i] += __shfl_xor(acc[i], 32);
    }
    if (o == 0) {
        float dr = dis[row];
        float d2 = dr * dr;
        uint4 ts = *(const uint4*)&tb[(size_t)row * 64 + 8 * fl];
        acc[0] = fmaf(__uint_as_float(ts.x << 16),         d2, acc[0]);
        acc[1] = fmaf(__uint_as_float(ts.x & 0xffff0000u), d2, acc[1]);
        acc[2] = fmaf(__uint_as_float(ts.y << 16),         d2, acc[2]);
        acc[3] = fmaf(__uint_as_float(ts.y & 0xffff0000u), d2, acc[3]);
        acc[4] = fmaf(__uint_as_float(ts.z << 16),         d2, acc[4]);
        acc[5] = fmaf(__uint_as_float(ts.z & 0xffff0000u), d2, acc[5]);
        acc[6] = fmaf(__uint_as_float(ts.w << 16),         d2, acc[6]);
        acc[7] = fmaf(__uint_as_float(ts.w & 0xffff0000u), d2, acc[7]);
        *(float4*)&a[(size_t)row * 64 + 8 * fl]     = make_float4(acc[0], acc[1], acc[2], acc[3]);
        *(float4*)&a[(size_t)row * 64 + 8 * fl + 4] = make_float4(acc[4], acc[5], acc[6], acc[7]);
    }
}

// ---------------- BatchNorm stats (vectorized float4) ----------------
__global__ void k_stats(const float* __restrict__ a, int n, float* __restrict__ stats) {
    __shared__ float ls[128];
    int tid = threadIdx.x;
    if (tid < 128) ls[tid] = 0.f;
    __syncthreads();
    int c0 = (tid & 15) * 4;      // column group of 4
    int rg = tid >> 4;            // 16 rows per block-iter
    float s[4] = {0.f, 0.f, 0.f, 0.f};
    float q[4] = {0.f, 0.f, 0.f, 0.f};
    for (int r = blockIdx.x * 16 + rg; r < n; r += gridDim.x * 16) {
        float4 v = *(const float4*)&a[(size_t)r * 64 + c0];
        s[0] += v.x; q[0] = fmaf(v.x, v.x, q[0]);
        s[1] += v.y; q[1] = fmaf(v.y, v.y, q[1]);
        s[2] += v.z; q[2] = fmaf(v.z, v.z, q[2]);
        s[3] += v.w; q[3] = fmaf(v.w, v.w, q[3]);
    }
    #pragma unroll
    for (int i = 0; i < 4; ++i) {
        atomicAdd(&ls[c0 + i], s[i]);
        atomicAdd(&ls[64 + c0 + i], q[i]);
    }
    __syncthreads();
    if (tid < 128) atomicAdd(&stats[tid], ls[tid]);
}

// ---------------- global mean pool (computes BN params per block, fused BN+ReLU) ----------
__global__ void k_pool2(const float* __restrict__ a, const float* __restrict__ stats,
                        const float* __restrict__ gamma, const float* __restrict__ beta,
                        const int* __restrict__ gs, int n, int G, float* __restrict__ out) {
    __shared__ float bnpL[128];
    int tid = threadIdx.x;
    if (tid < 64) {
        float inv_n = 1.f / (float)n;
        float mean = stats[tid] * inv_n;
        float var = stats[64 + tid] * inv_n - mean * mean;
        float s = gamma[tid] * rsqrtf(var + BN_EPS);
        bnpL[tid] = s;
        bnpL[64 + tid] = beta[tid] - mean * s;
    }
    __syncthreads();
    int lane = tid & 63;
    int wave = tid >> 6;
    int g = blockIdx.x * 4 + wave;
    if (g >= G) return;
    int s = gs[g], e = gs[g + 1];
    float sc = bnpL[lane], of = bnpL[64 + lane];
    float acc = 0.f;
    for (int r = s; r < e; ++r)
        acc += fmaxf(0.f, fmaf(a[(size_t)r * 64 + lane], sc, of));
    out[(size_t)g * 64 + lane] = acc / (float)max(e - s, 1);
}

// ---------------- launch ----------------
extern "C" void kernel_launch(void* const* d_in, const int* in_sizes, int n_in,
                              void* d_out, int out_size, void* d_ws, size_t ws_size,
                              hipStream_t stream) {
    const float* x     = (const float*)d_in[0];
    const int*   ei    = (const int*)d_in[1];
    const int*   batch = (const int*)d_in[2];
    const float* W1    = (const float*)d_in[3];
    const float* g1    = (const float*)d_in[5];
    const float* bt1   = (const float*)d_in[6];
    const float* W2    = (const float*)d_in[7];
    const float* g2    = (const float*)d_in[9];
    const float* bt2   = (const float*)d_in[10];

    const int N = in_sizes[0] / 64;
    const int E = in_sizes[1] / 2;
    const int G = out_size / 64;

    const int* src = ei;
    const int* dst = ei + E;

    const int nb = (N + 127) >> 7;           // buckets of 128 dst nodes (nb <= 1024)
    int sb = 0; while ((1 << sb) < N) ++sb;  // bits to hold src id
    const unsigned int smask = (1u << sb) - 1u;

    ushort* tb        = (ushort*)d_ws;                       // N*64 bf16
    float* a          = (float*)(tb + (size_t)N * 64);       // N*64 f32
    int2*  cw         = (int2*)(a + (size_t)N * 64);         // E {src, w}
    unsigned int* eb  = (unsigned int*)(cw + E);             // E (bucketed packed edges)
    float* dis        = (float*)(eb + E);                    // N
    int*   rowptr     = (int*)(dis + N);                     // N+1
    // zeroed region (one memset): bktcnt | stats(256)
    int*   bktcnt     = rowptr + N + 1;                      // nb
    float* stats      = (float*)(bktcnt + nb);               // 256 (two sets of 128)
    int*   bktoff     = (int*)(stats + 256);                 // nb+1
    int*   gpos       = bktoff + nb + 1;                     // nb
    int*   gs         = gpos + nb;                           // G+1

    float* out = (float*)d_out;

    const int mmBlocks = (N + 63) / 64;
    const int gaBlocks = (N + 3) / 4;
    const int nchunks  = (E + CCHUNK - 1) / CCHUNK;

    // ---- CSR build (bucketed, write-local) ----
    hipMemsetAsync(bktcnt, 0, (size_t)(nb + 256) * sizeof(int), stream);
    k_bhist<<<256, 256, 0, stream>>>(dst, E, nb, bktcnt, batch, N, G, gs);
    k_bscan<<<1, 256, 0, stream>>>(bktcnt, nb, N, bktoff, gpos, rowptr);
    k_partition<<<nchunks, 256, 0, stream>>>(src, dst, E, nb, sb, gpos, eb);
    k_row<<<nb, 256, 0, stream>>>(eb, bktoff, sb, N, dis, rowptr);
    k_csrfill<<<nb, 256, 0, stream>>>(eb, bktoff, rowptr, dis, sb, smask, N, cw);

    // ---- layer 1 ----
    k_matmul64t<<<mmBlocks, 256, 0, stream>>>(x, W1, nullptr, nullptr, nullptr, N, tb);
    k_gather<<<gaBlocks, 256, 0, stream>>>(cw, rowptr, dis, tb, N, a);
    k_stats<<<512, 256, 0, stream>>>(a, N, stats);

    // ---- layer 2 (BN1+ReLU fused into matmul input; BN params from raw stats) ----
    k_matmul64t<<<mmBlocks, 256, 0, stream>>>(a, W2, stats, g1, bt1, N, tb);
    k_gather<<<gaBlocks, 256, 0, stream>>>(cw, rowptr, dis, tb, N, a);
    k_stats<<<512, 256, 0, stream>>>(a, N, stats + 128);

    // ---- pool (BN2+ReLU fused; BN params from raw stats) ----
    k_pool2<<<(G + 3) / 4, 256, 0, stream>>>(a, stats + 128, g2, bt2, gs, N, G, out);
}